// Round 1
// baseline (327.360 us; speedup 1.0000x reference)
//
#include <hip/hip_runtime.h>

#define HID 512
#define GC  640
#define CC  320
#define GG  2
#define DHALF 128   // VQ_DIM / G

constexpr int BM = 64, BN = 128, BK = 32;

__global__ __launch_bounds__(256) void zero_acc(float* acc) {
    for (int i = threadIdx.x; i < GC; i += 256) acc[i] = 0.f;
}

// logits[m][640] = X[m][512] @ W[640][512]^T + bq
__global__ __launch_bounds__(256) void gemm_logits(
    const float* __restrict__ X, const float* __restrict__ W,
    const float* __restrict__ bq, float* __restrict__ L, int tok0)
{
    __shared__ float Xs[BK][BM + 4];   // [k][m]
    __shared__ float Ws[BK][BN + 4];   // [k][n]
    const int tid   = threadIdx.x;
    const int mloc0 = blockIdx.x * BM;      // chunk-local token base
    const int n0    = blockIdx.y * BN;
    const float* Xb = X + (size_t)(tok0 + mloc0) * HID;
    const float* Wb = W + (size_t)n0 * HID;

    const int tm = tid & 15;     // 16 threads along M
    const int tn = tid >> 4;     // 16 threads along N
    float acc[4][8];
#pragma unroll
    for (int i = 0; i < 4; ++i)
#pragma unroll
        for (int j = 0; j < 8; ++j) acc[i][j] = 0.f;

    const int lr = tid >> 3;     // 0..31 (row within tile load)
    const int lc = tid & 7;      // 0..7  (float4 column)

    for (int k0 = 0; k0 < HID; k0 += BK) {
        // X tile: 64 rows x 32 k  -> 512 float4, 2 per thread
#pragma unroll
        for (int it = 0; it < 2; ++it) {
            int row = lr + it * 32;
            float4 v = *(const float4*)(Xb + (size_t)row * HID + k0 + lc * 4);
            Xs[lc*4+0][row] = v.x; Xs[lc*4+1][row] = v.y;
            Xs[lc*4+2][row] = v.z; Xs[lc*4+3][row] = v.w;
        }
        // W tile: 128 rows x 32 k -> 1024 float4, 4 per thread
#pragma unroll
        for (int it = 0; it < 4; ++it) {
            int row = lr + it * 32;
            float4 v = *(const float4*)(Wb + (size_t)row * HID + k0 + lc * 4);
            Ws[lc*4+0][row] = v.x; Ws[lc*4+1][row] = v.y;
            Ws[lc*4+2][row] = v.z; Ws[lc*4+3][row] = v.w;
        }
        __syncthreads();
#pragma unroll
        for (int k = 0; k < BK; ++k) {
            float4 a  = *(const float4*)&Xs[k][tm * 4];
            float4 b0 = *(const float4*)&Ws[k][tn * 8];
            float4 b1 = *(const float4*)&Ws[k][tn * 8 + 4];
            float av[4] = {a.x, a.y, a.z, a.w};
            float bv[8] = {b0.x, b0.y, b0.z, b0.w, b1.x, b1.y, b1.z, b1.w};
#pragma unroll
            for (int i = 0; i < 4; ++i)
#pragma unroll
                for (int j = 0; j < 8; ++j)
                    acc[i][j] = fmaf(av[i], bv[j], acc[i][j]);
        }
        __syncthreads();
    }
    // epilogue: + bias, store logits (chunk-local rows)
#pragma unroll
    for (int i = 0; i < 4; ++i) {
        int row = mloc0 + tm * 4 + i;
#pragma unroll
        for (int j = 0; j < 8; j += 4) {
            int col = n0 + tn * 8 + j;
            float4 o;
            o.x = acc[i][j+0] + bq[col+0];
            o.y = acc[i][j+1] + bq[col+1];
            o.z = acc[i][j+2] + bq[col+2];
            o.w = acc[i][j+3] + bq[col+3];
            *(float4*)&L[(size_t)row * GC + col] = o;
        }
    }
}

// One wave per (token, group)-pair stream: softmax-mean accumulate + argmax + gather.
// Block = 64 tokens: waves 0,1 -> group 0 (tokens 0..31 / 32..63); waves 2,3 -> group 1.
__global__ __launch_bounds__(256) void postproc(
    const float* __restrict__ L, const float* __restrict__ gum,
    const float* __restrict__ cv, float* __restrict__ out,
    float* __restrict__ meanAcc, int tok0)
{
    __shared__ float smean[GC];
    for (int i = threadIdx.x; i < GC; i += 256) smean[i] = 0.f;
    __syncthreads();

    const int lane  = threadIdx.x & 63;
    const int wid   = threadIdx.x >> 6;          // 0..3
    const int g     = wid >> 1;                  // group
    const int tloc0 = blockIdx.x * 64 + (wid & 1) * 32;

    float macc[5] = {0.f, 0.f, 0.f, 0.f, 0.f};

    for (int t = 0; t < 32; ++t) {
        const int tloc  = tloc0 + t;
        const int tglob = tok0 + tloc;
        const float* lrow = L   + (size_t)tloc * GC + g * CC;
        const float* grow = gum + ((size_t)tglob * GG + g) * CC;
        float l[5], gm[5];
#pragma unroll
        for (int j = 0; j < 5; ++j) {
            int c = lane + j * 64;               // 320 = 5*64, always valid
            l[j]  = lrow[c];
            gm[j] = grow[c];
        }
        // plain softmax(logits) for mean_p
        float mx = fmaxf(fmaxf(fmaxf(l[0], l[1]), fmaxf(l[2], l[3])), l[4]);
#pragma unroll
        for (int m = 32; m; m >>= 1) mx = fmaxf(mx, __shfl_xor(mx, m, 64));
        float e[5], s = 0.f;
#pragma unroll
        for (int j = 0; j < 5; ++j) { e[j] = __expf(l[j] - mx); s += e[j]; }
#pragma unroll
        for (int m = 32; m; m >>= 1) s += __shfl_xor(s, m, 64);
        float inv = 1.f / s;
#pragma unroll
        for (int j = 0; j < 5; ++j) macc[j] += e[j] * inv;

        // argmax of (logits + gumbel); ties -> lowest index (numpy semantics)
        float bv = l[0] + gm[0]; int bi = lane;
#pragma unroll
        for (int j = 1; j < 5; ++j) {
            float v = l[j] + gm[j]; int c = lane + j * 64;
            if (v > bv || (v == bv && c < bi)) { bv = v; bi = c; }
        }
#pragma unroll
        for (int m = 32; m; m >>= 1) {
            float ov = __shfl_xor(bv, m, 64);
            int   oi = __shfl_xor(bi, m, 64);
            if (ov > bv || (ov == bv && oi < bi)) { bv = ov; bi = oi; }
        }
        // gather selected codevector (128 floats; 1 float2 per lane, coalesced)
        const float* cvp = cv + (size_t)(g * CC + bi) * DHALF;
        float2 cvv = *(const float2*)(cvp + lane * 2);
        *(float2*)(out + (size_t)tglob * 256 + g * DHALF + lane * 2) = cvv;
    }
    // fold per-wave softmax partials into block LDS, then one global atomic pass
#pragma unroll
    for (int j = 0; j < 5; ++j)
        atomicAdd(&smean[g * CC + lane + j * 64], macc[j]);
    __syncthreads();
    for (int i = threadIdx.x; i < GC; i += 256)
        atomicAdd(&meanAcc[i], smean[i]);
}

__global__ __launch_bounds__(256) void perpk(
    const float* __restrict__ meanAcc, float* __restrict__ outp, int ntot)
{
    __shared__ float red0[256];
    __shared__ float red1[256];
    const float invn = 1.f / (float)ntot;
    float h0 = 0.f, h1 = 0.f;
    for (int c = threadIdx.x; c < CC; c += 256) {
        float p0 = meanAcc[c]      * invn;
        float p1 = meanAcc[CC + c] * invn;
        h0 -= p0 * logf(p0 + 1e-7f);
        h1 -= p1 * logf(p1 + 1e-7f);
    }
    red0[threadIdx.x] = h0; red1[threadIdx.x] = h1;
    __syncthreads();
    for (int s = 128; s; s >>= 1) {
        if (threadIdx.x < (unsigned)s) {
            red0[threadIdx.x] += red0[threadIdx.x + s];
            red1[threadIdx.x] += red1[threadIdx.x + s];
        }
        __syncthreads();
    }
    if (threadIdx.x == 0) outp[0] = expf(red0[0]) + expf(red1[0]);
}

extern "C" void kernel_launch(void* const* d_in, const int* in_sizes, int n_in,
                              void* d_out, int out_size, void* d_ws, size_t ws_size,
                              hipStream_t stream) {
    const float* x      = (const float*)d_in[0];
    const float* gumbel = (const float*)d_in[1];
    const float* Wq     = (const float*)d_in[2];
    const float* bq     = (const float*)d_in[3];
    const float* cv     = (const float*)d_in[4];
    float* out = (float*)d_out;

    const int NT = in_sizes[0] / HID;   // 32768 tokens

    float* meanAcc = (float*)d_ws;
    float* Lbuf    = (float*)((char*)d_ws + 4096);

    // chunk so the logits buffer fits the workspace
    size_t avail = ws_size > 4096 ? ws_size - 4096 : 0;
    long maxTok = (long)(avail / (GC * sizeof(float)));
    int CH = (int)((maxTok / 64) * 64);
    if (CH > NT) CH = NT;
    if (CH < 64) CH = 64;   // assume ws is at least ~170 KB

    zero_acc<<<1, 256, 0, stream>>>(meanAcc);

    for (int t0 = 0; t0 < NT; t0 += CH) {
        int cur = NT - t0 < CH ? NT - t0 : CH;
        dim3 ggrid(cur / BM, GC / BN);
        gemm_logits<<<ggrid, 256, 0, stream>>>(x, Wq, bq, Lbuf, t0);
        postproc<<<cur / 64, 256, 0, stream>>>(Lbuf, gumbel, cv, out, meanAcc, t0);
    }
    perpk<<<1, 256, 0, stream>>>(meanAcc, out + (size_t)out_size - 1, NT);
}